// Round 1
// baseline (90278.119 us; speedup 1.0000x reference)
//
#include <hip/hip_runtime.h>
#include <hip/hip_bf16.h>

// SLAHead decode: B=64 batches, T=784 spatial, C=H=512, 501 steps.
// Structure: setup kernels (transpose->bf16, feat_proj GEMM, init) +
// one persistent kernel (256 blocks x 1024 thr, 1 block/CU co-resident)
// with a custom device-scope grid barrier, 3 barriers per step.

#define NB 64
#define TT 784
#define CC 512
#define HH 512
#define NCLS 30
#define LREG 8
#define STEPS 501
#define GRID_MAIN 256
#define THR_MAIN 1024

struct SlaP {
  // workspace
  __hip_bfloat16* feat16;   // [B][T][C] bf16
  __hip_bfloat16* fp16;     // [B][T][H] bf16 (feat_proj)
  float* hidT;              // [2][H][B] transposed hidden, ping-pong
  float* hproj;             // [B][H]
  float* h1sg;              // [B][H]
  float* h1lg;              // [B][H]
  float* ctxT;              // [C][B] transposed context accumulator (raw, * w)
  float* wsumT;             // [B]
  int*   chars;             // [B]
  unsigned* bar;            // [0]=cnt [1]=gen
  // weights (device inputs, fp32)
  const float *score_w, *w_ih, *w_hh, *b_ih, *b_hh;
  const float *h2h_w, *h2h_b, *sg1_w, *sg1_b, *sg2_w, *sg2_b;
  const float *lg1_w, *lg1_b, *lg2_w, *lg2_b;
  // outputs
  float *out_probs, *out_loc;
};

__device__ __forceinline__ float lo16(unsigned v){ return __uint_as_float(v << 16); }
__device__ __forceinline__ float hi16(unsigned v){ return __uint_as_float(v & 0xffff0000u); }

__device__ __forceinline__ float tanh_fast(float x){
  // 1 - 2/(1+e^{2x}); inf-safe at both ends.
  float ex = __expf(2.f * x);
  return 1.f - 2.f * __builtin_amdgcn_rcpf(ex + 1.f);
}
__device__ __forceinline__ float sigmoid_fast(float x){
  return __builtin_amdgcn_rcpf(1.f + __expf(-x));
}
__device__ __forceinline__ float warp_sum(float v){
  #pragma unroll
  for (int m = 32; m > 0; m >>= 1) v += __shfl_xor(v, m, 64);
  return v;
}
__device__ __forceinline__ float warp_max(float v){
  #pragma unroll
  for (int m = 32; m > 0; m >>= 1) v = fmaxf(v, __shfl_xor(v, m, 64));
  return v;
}
__device__ __forceinline__ int warp_min_i(int v){
  #pragma unroll
  for (int m = 32; m > 0; m >>= 1) v = min(v, __shfl_xor(v, m, 64));
  return v;
}

// grid barrier: 256 co-resident blocks; monotone generation counter.
__device__ __forceinline__ void gbar(unsigned* cnt, unsigned* gen, unsigned target){
  __syncthreads();
  if (threadIdx.x == 0){
    __threadfence();   // release prior plain stores (agent scope)
    unsigned prev = __hip_atomic_fetch_add(cnt, 1u, __ATOMIC_ACQ_REL, __HIP_MEMORY_SCOPE_AGENT);
    if (prev == GRID_MAIN - 1){
      __hip_atomic_store(cnt, 0u, __ATOMIC_RELAXED, __HIP_MEMORY_SCOPE_AGENT);
      __hip_atomic_store(gen, target, __ATOMIC_RELEASE, __HIP_MEMORY_SCOPE_AGENT);
    } else {
      unsigned g;
      do {
        __builtin_amdgcn_s_sleep(2);
        g = __hip_atomic_load(gen, __ATOMIC_ACQUIRE, __HIP_MEMORY_SCOPE_AGENT);
      } while (g < target);
    }
    __threadfence();   // acquire: invalidate L1/L2 before dependent plain loads
  }
  __syncthreads();
}

// ---------------- setup kernels ----------------

__global__ void k_init(SlaP p){
  int idx = blockIdx.x * blockDim.x + threadIdx.x;  // 128*256 = 32768 threads
  if (idx < 512*64){ p.hidT[idx] = 0.f; p.ctxT[idx] = 0.f; }
  if (idx < 64*512) p.hproj[idx] = p.h2h_b[idx & 511];   // hidden_0 = 0
  if (idx < 64){ p.wsumT[idx] = 0.f; p.chars[idx] = 0; }
  if (idx < 2) p.bar[idx] = 0u;
}

// feat16[b][t][c] = bf16(fea[b][c][t]) via LDS-tiled transpose
__global__ void k_transpose(const float* __restrict__ fea, __hip_bfloat16* __restrict__ feat16){
  __shared__ float tile[64][65];
  const int b = blockIdx.z, t0 = blockIdx.x * 64, c0 = blockIdx.y * 64;
  #pragma unroll
  for (int r = 0; r < 16; ++r){
    int idx = threadIdx.x + 256*r;
    int ci = idx >> 6, tj = idx & 63;
    float v = 0.f;
    if (t0 + tj < TT) v = fea[((size_t)b*CC + (c0+ci))*TT + t0 + tj];
    tile[ci][tj] = v;
  }
  __syncthreads();
  #pragma unroll
  for (int r = 0; r < 16; ++r){
    int idx = threadIdx.x + 256*r;
    int tj = idx >> 6, ci = idx & 63;
    if (t0 + tj < TT)
      feat16[((size_t)b*TT + t0 + tj)*CC + c0 + ci] = __float2bfloat16(tile[ci][tj]);
  }
}

// fp16[b][t][h] = bf16( sum_c fea[b][c][t] * i2h[h][c] )  (register-blocked 4x4)
__global__ void k_fpgemm(const float* __restrict__ fea, const float* __restrict__ i2h,
                         __hip_bfloat16* __restrict__ fp16){
  const int b = blockIdx.z, t0 = blockIdx.x * 64, h0 = blockIdx.y * 64;
  const int tx = threadIdx.x & 15, ty = threadIdx.x >> 4;
  const int tb = t0 + tx*4, hb = h0 + ty*4;
  const int ts = (tb < TT) ? tb : 0;           // clamp to stay in-bounds
  const float* A = fea + (size_t)b*CC*TT;
  float acc[4][4];
  #pragma unroll
  for (int j = 0; j < 4; ++j)
    #pragma unroll
    for (int i2 = 0; i2 < 4; ++i2) acc[j][i2] = 0.f;
  for (int k = 0; k < CC; ++k){
    const float4 a4 = *(const float4*)&A[(size_t)k*TT + ts];
    float bv0 = i2h[(size_t)(hb+0)*CC + k];
    float bv1 = i2h[(size_t)(hb+1)*CC + k];
    float bv2 = i2h[(size_t)(hb+2)*CC + k];
    float bv3 = i2h[(size_t)(hb+3)*CC + k];
    acc[0][0] += bv0*a4.x; acc[0][1] += bv0*a4.y; acc[0][2] += bv0*a4.z; acc[0][3] += bv0*a4.w;
    acc[1][0] += bv1*a4.x; acc[1][1] += bv1*a4.y; acc[1][2] += bv1*a4.z; acc[1][3] += bv1*a4.w;
    acc[2][0] += bv2*a4.x; acc[2][1] += bv2*a4.y; acc[2][2] += bv2*a4.z; acc[2][3] += bv2*a4.w;
    acc[3][0] += bv3*a4.x; acc[3][1] += bv3*a4.y; acc[3][2] += bv3*a4.z; acc[3][3] += bv3*a4.w;
  }
  if (tb < TT){
    #pragma unroll
    for (int j = 0; j < 4; ++j)
      #pragma unroll
      for (int i2 = 0; i2 < 4; ++i2)
        fp16[((size_t)b*TT + tb + i2)*CC + hb + j] = __float2bfloat16(acc[j][i2]);
  }
}

// ---------------- persistent decode kernel ----------------

__global__ void __launch_bounds__(THR_MAIN, 4) sla_main(SlaP p){
  const int tid  = threadIdx.x;
  const int lane = tid & 63;
  const int wv   = tid >> 6;       // 16 waves
  const int blk  = blockIdx.x;     // 256 blocks
  __shared__ float sm[7000];       // 28 KB, unioned across phases

  const int ab = blk >> 2;         // attention: batch
  const int aslice = blk & 3;      // attention: t-slice (4 x 196)
  float svr[8];
  #pragma unroll
  for (int k = 0; k < 8; ++k) svr[k] = p.score_w[lane*8 + k];

  unsigned bid = 0;

  for (int i = 0; i <= STEPS; ++i){
    //================ P1: finals(step i-1) + attention(step i) ================
    if (i > 0 && blk < NB){
      const int fb = blk;
      for (int task = wv; task < 38; task += 16){
        const float* wrow; const float* src; float bias;
        if (task < 30){ wrow = p.sg2_w + task*512; bias = p.sg2_b[task]; src = p.h1sg + fb*512; }
        else          { wrow = p.lg2_w + (task-30)*512; bias = p.lg2_b[task-30]; src = p.h1lg + fb*512; }
        float s = 0.f;
        #pragma unroll
        for (int k = 0; k < 8; ++k) s += wrow[lane + 64*k] * src[lane + 64*k];
        s = warp_sum(s);
        if (task < 30){ if (lane == 0) sm[520 + task] = s + bias; }
        else if (lane == 0)
          p.out_loc[(size_t)fb*(STEPS*LREG) + (size_t)(i-1)*LREG + (task-30)] = sigmoid_fast(s + bias);
      }
    }
    __syncthreads();
    if (i > 0 && blk < NB && wv == 0){
      float sv_ = (lane < 30) ? sm[520 + lane] : -3.4e38f;
      float m = warp_max(sv_);
      float e = (lane < 30) ? __expf(sv_ - m) : 0.f;
      float ssum = warp_sum(e);
      if (lane < 30)
        p.out_probs[(size_t)blk*(STEPS*NCLS) + (size_t)(i-1)*NCLS + lane] = e / ssum;
      int cand = (lane < 30 && sv_ == m) ? lane : 1000;   // argmax = first max
      cand = warp_min_i(cand);
      if (lane == 0) p.chars[blk] = cand;
    }
    if (i == STEPS) break;           // finals(500) done; no more phases
    if (tid >= 512) sm[tid - 512] = 0.f;   // zero lds_ctx[0..512)
    if (tid == 0) sm[512] = 0.f;           // lds_wsum
    __syncthreads();
    {
      // attention: e = sum_h tanh(fp + hproj)*sv ; w=exp(e) (|e|<~8, no max needed)
      float hpr[8];
      #pragma unroll
      for (int k = 0; k < 8; ++k) hpr[k] = p.hproj[ab*512 + lane*8 + k];
      float acc[8] = {0,0,0,0,0,0,0,0};
      float wsr = 0.f;
      const int tl0 = aslice * 196;
      const unsigned short* fpB = (const unsigned short*)p.fp16 + ((size_t)ab*TT)*512;
      const unsigned short* ftB = (const unsigned short*)p.feat16 + ((size_t)ab*TT)*512;
      for (int it = 0; it < 13; ++it){
        int tl = wv + 16*it;
        if (tl < 196){
          const size_t rowo = (size_t)(tl0 + tl)*512 + lane*8;
          const uint4 ufp = *(const uint4*)(fpB + rowo);
          float e0 = 0.f, x;
          x = lo16(ufp.x)+hpr[0]; e0 += tanh_fast(x)*svr[0];
          x = hi16(ufp.x)+hpr[1]; e0 += tanh_fast(x)*svr[1];
          x = lo16(ufp.y)+hpr[2]; e0 += tanh_fast(x)*svr[2];
          x = hi16(ufp.y)+hpr[3]; e0 += tanh_fast(x)*svr[3];
          x = lo16(ufp.z)+hpr[4]; e0 += tanh_fast(x)*svr[4];
          x = hi16(ufp.z)+hpr[5]; e0 += tanh_fast(x)*svr[5];
          x = lo16(ufp.w)+hpr[6]; e0 += tanh_fast(x)*svr[6];
          x = hi16(ufp.w)+hpr[7]; e0 += tanh_fast(x)*svr[7];
          e0 = warp_sum(e0);
          float wgt = __expf(e0);
          const uint4 uft = *(const uint4*)(ftB + rowo);
          acc[0] += wgt*lo16(uft.x); acc[1] += wgt*hi16(uft.x);
          acc[2] += wgt*lo16(uft.y); acc[3] += wgt*hi16(uft.y);
          acc[4] += wgt*lo16(uft.z); acc[5] += wgt*hi16(uft.z);
          acc[6] += wgt*lo16(uft.w); acc[7] += wgt*hi16(uft.w);
          wsr += wgt;
        }
      }
      #pragma unroll
      for (int k = 0; k < 8; ++k) atomicAdd(&sm[lane*8 + k], acc[k]);
      if (lane == 0) atomicAdd(&sm[512], wsr);
    }
    __syncthreads();
    if (tid < 512) atomicAdd(&p.ctxT[tid*64 + ab], sm[tid]);
    if (tid == 512) atomicAdd(&p.wsumT[ab], sm[512]);
    gbar(p.bar, p.bar + 1, ++bid);
    //================ P2: GRU (lane=batch, weight rows broadcast from LDS) ================
    {
      const int j0 = blk * 2;               // 2 hidden outputs per block
      float* lw = sm;                       // 12 rows x 516 (pad)
      float* gg = sm + 12*516;              // [12][64] partial dots
      for (int idx = tid; idx < 12*512; idx += THR_MAIN){
        int r = idx >> 9, k = idx & 511;
        float v;
        if (r < 6){ int g = r >> 1, jj = r & 1;
          v = p.w_ih[(size_t)(g*512 + j0 + jj)*542 + k];
        } else { int r2 = r - 6; int g = r2 >> 1, jj = r2 & 1;
          v = p.w_hh[(size_t)(g*512 + j0 + jj)*512 + k];
        }
        lw[r*516 + k] = v;
      }
      if (tid < 768) gg[tid] = 0.f;
      __syncthreads();
      const float* hidC = p.hidT + (i & 1)*(512*64);
      float acc[12];
      #pragma unroll
      for (int r = 0; r < 12; ++r) acc[r] = 0.f;
      const int kb = wv * 32;               // 16 waves cover k=0..511
      for (int kk = 0; kk < 32; kk += 4){
        const int k = kb + kk;
        float xv0 = p.ctxT[(k+0)*64 + lane];
        float xv1 = p.ctxT[(k+1)*64 + lane];
        float xv2 = p.ctxT[(k+2)*64 + lane];
        float xv3 = p.ctxT[(k+3)*64 + lane];
        float hv0 = hidC[(k+0)*64 + lane];
        float hv1 = hidC[(k+1)*64 + lane];
        float hv2 = hidC[(k+2)*64 + lane];
        float hv3 = hidC[(k+3)*64 + lane];
        #pragma unroll
        for (int r = 0; r < 6; ++r){
          const float4 w4 = *(const float4*)&lw[r*516 + k];
          acc[r] += w4.x*xv0 + w4.y*xv1 + w4.z*xv2 + w4.w*xv3;
        }
        #pragma unroll
        for (int r = 6; r < 12; ++r){
          const float4 w4 = *(const float4*)&lw[r*516 + k];
          acc[r] += w4.x*hv0 + w4.y*hv1 + w4.z*hv2 + w4.w*hv3;
        }
      }
      #pragma unroll
      for (int r = 0; r < 12; ++r) atomicAdd(&gg[r*64 + lane], acc[r]);
      __syncthreads();
      if (tid < 128){
        int jj = tid >> 6, b = tid & 63;
        float inv = 1.f / p.wsumT[b];
        int ch = p.chars[b];
        float gi[3], gh[3];
        #pragma unroll
        for (int g = 0; g < 3; ++g){
          int row = g*512 + j0 + jj;
          gi[g] = gg[(g*2 + jj)*64 + b]*inv + p.w_ih[(size_t)row*542 + 512 + ch] + p.b_ih[row];
          gh[g] = gg[(6 + g*2 + jj)*64 + b] + p.b_hh[row];
        }
        float r_ = sigmoid_fast(gi[0] + gh[0]);
        float z_ = sigmoid_fast(gi[1] + gh[1]);
        float n_ = tanh_fast(gi[2] + r_*gh[2]);
        float hold = hidC[(j0 + jj)*64 + b];
        p.hidT[((i+1) & 1)*(512*64) + (j0 + jj)*64 + b] = (1.f - z_)*n_ + z_*hold;
      }
    }
    gbar(p.bar, p.bar + 1, ++bid);
    //================ P3: heads (hproj / sg1 / lg1 rows) + zero ctx ================
    {
      const int r0 = blk * 6;               // 1536 rows over 256 blocks
      float* lw = sm;                       // 6 x 516
      float* ha = sm + 6*516;               // [6][64]
      for (int idx = tid; idx < 6*512; idx += THR_MAIN){
        int r = idx >> 9, k = idx & 511;
        int rg = r0 + r; int head = rg >> 9; int j = rg & 511;
        const float* wm = (head == 0) ? p.h2h_w : (head == 1) ? p.sg1_w : p.lg1_w;
        lw[r*516 + k] = wm[(size_t)j*512 + k];
      }
      if (tid < 384) ha[tid] = 0.f;
      __syncthreads();
      const float* hidN = p.hidT + ((i+1) & 1)*(512*64);
      float acc[6];
      #pragma unroll
      for (int r = 0; r < 6; ++r) acc[r] = 0.f;
      const int kb = wv * 32;
      for (int kk = 0; kk < 32; kk += 4){
        const int k = kb + kk;
        float h0 = hidN[(k+0)*64 + lane];
        float h1 = hidN[(k+1)*64 + lane];
        float h2 = hidN[(k+2)*64 + lane];
        float h3 = hidN[(k+3)*64 + lane];
        #pragma unroll
        for (int r = 0; r < 6; ++r){
          const float4 w4 = *(const float4*)&lw[r*516 + k];
          acc[r] += w4.x*h0 + w4.y*h1 + w4.z*h2 + w4.w*h3;
        }
      }
      #pragma unroll
      for (int r = 0; r < 6; ++r) atomicAdd(&ha[r*64 + lane], acc[r]);
      __syncthreads();
      if (tid < 384){
        int r = tid >> 6, b = tid & 63;
        int rg = r0 + r; int head = rg >> 9; int j = rg & 511;
        float bias = (head == 0) ? p.h2h_b[j] : (head == 1) ? p.sg1_b[j] : p.lg1_b[j];
        float v = ha[r*64 + b] + bias;
        float* dst = (head == 0) ? p.hproj : (head == 1) ? p.h1sg : p.h1lg;
        dst[b*512 + j] = v;
      } else if (tid >= 512 && tid < 640){
        p.ctxT[blk*128 + (tid - 512)] = 0.f;      // zero for next step's atomics
      } else if (blk == 0 && tid >= 640 && tid < 704){
        p.wsumT[tid - 640] = 0.f;
      }
    }
    gbar(p.bar, p.bar + 1, ++bid);
  }
}

extern "C" void kernel_launch(void* const* d_in, const int* in_sizes, int n_in,
                              void* d_out, int out_size, void* d_ws, size_t ws_size,
                              hipStream_t stream){
  (void)in_sizes; (void)n_in; (void)out_size; (void)ws_size;
  char* w = (char*)d_ws;
  size_t off = 0;
  auto carve = [&](size_t bytes) -> char* {
    char* r = w + off; off += (bytes + 255) & ~(size_t)255; return r;
  };
  SlaP p;
  p.feat16 = (__hip_bfloat16*)carve((size_t)NB*TT*CC*2);
  p.fp16   = (__hip_bfloat16*)carve((size_t)NB*TT*HH*2);
  p.hidT   = (float*)carve((size_t)2*512*64*4);
  p.hproj  = (float*)carve((size_t)64*512*4);
  p.h1sg   = (float*)carve((size_t)64*512*4);
  p.h1lg   = (float*)carve((size_t)64*512*4);
  p.ctxT   = (float*)carve((size_t)512*64*4);
  p.wsumT  = (float*)carve(64*4);
  p.chars  = (int*)carve(64*4);
  p.bar    = (unsigned*)carve(256);

  p.score_w = (const float*)d_in[4];
  p.w_ih  = (const float*)d_in[5];  p.w_hh  = (const float*)d_in[6];
  p.b_ih  = (const float*)d_in[7];  p.b_hh  = (const float*)d_in[8];
  p.h2h_w = (const float*)d_in[2];  p.h2h_b = (const float*)d_in[3];
  p.sg1_w = (const float*)d_in[9];  p.sg1_b = (const float*)d_in[10];
  p.sg2_w = (const float*)d_in[11]; p.sg2_b = (const float*)d_in[12];
  p.lg1_w = (const float*)d_in[13]; p.lg1_b = (const float*)d_in[14];
  p.lg2_w = (const float*)d_in[15]; p.lg2_b = (const float*)d_in[16];
  p.out_probs = (float*)d_out;
  p.out_loc   = p.out_probs + (size_t)NB*STEPS*NCLS;

  const float* fea = (const float*)d_in[0];
  const float* i2h = (const float*)d_in[1];

  k_init<<<128, 256, 0, stream>>>(p);
  k_transpose<<<dim3(13, 8, 64), 256, 0, stream>>>(fea, p.feat16);
  k_fpgemm<<<dim3(13, 8, 64), 256, 0, stream>>>(fea, i2h, p.fp16);
  sla_main<<<GRID_MAIN, THR_MAIN, 0, stream>>>(p);
}

// Round 2
// 47267.935 us; speedup vs baseline: 1.9099x; 1.9099x over previous
//
#include <hip/hip_runtime.h>
#include <hip/hip_bf16.h>

// SLAHead decode: B=64, T=784, C=H=512, 501 steps.
// Persistent kernel, 256 blocks x 1024 thr (1 block/CU co-resident).
// Fence-free protocol: all cross-block state uses relaxed agent-scope
// atomics (coherence-point ops, no L2 wb/inv scans); grid barrier is a
// monotone two-level counter with relaxed atomics only.

#define NB 64
#define TT 784
#define CC 512
#define HH 512
#define NCLS 30
#define LREG 8
#define STEPS 501
#define GRID_MAIN 256
#define THR_MAIN 1024

struct SlaP {
  __hip_bfloat16* feat16;   // [B][T][C]
  __hip_bfloat16* fp16;     // [B][T][H]
  float* hidT;              // [2][H][B] ping-pong
  float* hproj;             // [B][H]
  float* h1sg;              // [B][H]
  float* h1lg;              // [B][H]
  float* ctxP;              // [4][C][B] per-slice raw context partials
  float* wsumP;             // [4][B]
  int*   chars;             // [B]
  unsigned* bar;            // [0]=master cnt, [64]=gen, [8+32x]=per-XCD cnt
  const float *score_w, *w_ih, *w_hh, *b_ih, *b_hh;
  const float *h2h_w, *h2h_b, *sg1_w, *sg1_b, *sg2_w, *sg2_b;
  const float *lg1_w, *lg1_b, *lg2_w, *lg2_b;
  float *out_probs, *out_loc;
};

__device__ __forceinline__ float lo16(unsigned v){ return __uint_as_float(v << 16); }
__device__ __forceinline__ float hi16(unsigned v){ return __uint_as_float(v & 0xffff0000u); }

__device__ __forceinline__ float cld(const float* p){
  return __hip_atomic_load(p, __ATOMIC_RELAXED, __HIP_MEMORY_SCOPE_AGENT);
}
__device__ __forceinline__ void cst(float* p, float v){
  __hip_atomic_store(p, v, __ATOMIC_RELAXED, __HIP_MEMORY_SCOPE_AGENT);
}
__device__ __forceinline__ int cldi(const int* p){
  return __hip_atomic_load(p, __ATOMIC_RELAXED, __HIP_MEMORY_SCOPE_AGENT);
}
__device__ __forceinline__ void csti(int* p, int v){
  __hip_atomic_store(p, v, __ATOMIC_RELAXED, __HIP_MEMORY_SCOPE_AGENT);
}

__device__ __forceinline__ float tanh_fast(float x){
  float ex = __expf(2.f * x);
  return 1.f - 2.f * __builtin_amdgcn_rcpf(ex + 1.f);
}
__device__ __forceinline__ float sigmoid_fast(float x){
  return __builtin_amdgcn_rcpf(1.f + __expf(-x));
}
__device__ __forceinline__ float warp_sum(float v){
  #pragma unroll
  for (int m = 32; m > 0; m >>= 1) v += __shfl_xor(v, m, 64);
  return v;
}
__device__ __forceinline__ float warp_max(float v){
  #pragma unroll
  for (int m = 32; m > 0; m >>= 1) v = fmaxf(v, __shfl_xor(v, m, 64));
  return v;
}
__device__ __forceinline__ int warp_min_i(int v){
  #pragma unroll
  for (int m = 32; m > 0; m >>= 1) v = min(v, __shfl_xor(v, m, 64));
  return v;
}

// Monotone fence-free grid barrier. Counters never reset; barrier n's
// per-XCD target is 32*n, master target 8*n. All ops relaxed agent scope;
// __syncthreads' implied vmcnt(0) drains each wave's coherent stores.
__device__ __forceinline__ void gbar(unsigned* bar, unsigned target){
  __syncthreads();
  if (threadIdx.x == 0){
    unsigned* c8 = bar + 8 + (blockIdx.x & 7) * 32;
    unsigned p = __hip_atomic_fetch_add(c8, 1u, __ATOMIC_RELAXED, __HIP_MEMORY_SCOPE_AGENT);
    if (p == 32u * target - 1u){
      unsigned pm = __hip_atomic_fetch_add(bar, 1u, __ATOMIC_RELAXED, __HIP_MEMORY_SCOPE_AGENT);
      if (pm == 8u * target - 1u)
        __hip_atomic_store(bar + 64, target, __ATOMIC_RELAXED, __HIP_MEMORY_SCOPE_AGENT);
    }
    while (__hip_atomic_load(bar + 64, __ATOMIC_RELAXED, __HIP_MEMORY_SCOPE_AGENT) < target)
      __builtin_amdgcn_s_sleep(1);
  }
  __syncthreads();
}

// ---------------- setup kernels ----------------

__global__ void k_init(SlaP p){
  int idx = blockIdx.x * blockDim.x + threadIdx.x;  // 32768 threads
  if (idx < 512*64) p.hidT[idx] = 0.f;
  if (idx < 64*512) p.hproj[idx] = p.h2h_b[idx & 511];
  if (idx < 64) p.chars[idx] = 0;
  if (idx < 512) p.bar[idx] = 0u;
}

__global__ void k_transpose(const float* __restrict__ fea, __hip_bfloat16* __restrict__ feat16){
  __shared__ float tile[64][65];
  const int b = blockIdx.z, t0 = blockIdx.x * 64, c0 = blockIdx.y * 64;
  #pragma unroll
  for (int r = 0; r < 16; ++r){
    int idx = threadIdx.x + 256*r;
    int ci = idx >> 6, tj = idx & 63;
    float v = 0.f;
    if (t0 + tj < TT) v = fea[((size_t)b*CC + (c0+ci))*TT + t0 + tj];
    tile[ci][tj] = v;
  }
  __syncthreads();
  #pragma unroll
  for (int r = 0; r < 16; ++r){
    int idx = threadIdx.x + 256*r;
    int tj = idx >> 6, ci = idx & 63;
    if (t0 + tj < TT)
      feat16[((size_t)b*TT + t0 + tj)*CC + c0 + ci] = __float2bfloat16(tile[ci][tj]);
  }
}

__global__ void k_fpgemm(const float* __restrict__ fea, const float* __restrict__ i2h,
                         __hip_bfloat16* __restrict__ fp16){
  const int b = blockIdx.z, t0 = blockIdx.x * 64, h0 = blockIdx.y * 64;
  const int tx = threadIdx.x & 15, ty = threadIdx.x >> 4;
  const int tb = t0 + tx*4, hb = h0 + ty*4;
  const int ts = (tb < TT) ? tb : 0;
  const float* A = fea + (size_t)b*CC*TT;
  float acc[4][4];
  #pragma unroll
  for (int j = 0; j < 4; ++j)
    #pragma unroll
    for (int i2 = 0; i2 < 4; ++i2) acc[j][i2] = 0.f;
  for (int k = 0; k < CC; ++k){
    const float4 a4 = *(const float4*)&A[(size_t)k*TT + ts];
    float bv0 = i2h[(size_t)(hb+0)*CC + k];
    float bv1 = i2h[(size_t)(hb+1)*CC + k];
    float bv2 = i2h[(size_t)(hb+2)*CC + k];
    float bv3 = i2h[(size_t)(hb+3)*CC + k];
    acc[0][0] += bv0*a4.x; acc[0][1] += bv0*a4.y; acc[0][2] += bv0*a4.z; acc[0][3] += bv0*a4.w;
    acc[1][0] += bv1*a4.x; acc[1][1] += bv1*a4.y; acc[1][2] += bv1*a4.z; acc[1][3] += bv1*a4.w;
    acc[2][0] += bv2*a4.x; acc[2][1] += bv2*a4.y; acc[2][2] += bv2*a4.z; acc[2][3] += bv2*a4.w;
    acc[3][0] += bv3*a4.x; acc[3][1] += bv3*a4.y; acc[3][2] += bv3*a4.z; acc[3][3] += bv3*a4.w;
  }
  if (tb < TT){
    #pragma unroll
    for (int j = 0; j < 4; ++j)
      #pragma unroll
      for (int i2 = 0; i2 < 4; ++i2)
        fp16[((size_t)b*TT + tb + i2)*CC + hb + j] = __float2bfloat16(acc[j][i2]);
  }
}

// ---------------- persistent decode kernel ----------------

__global__ void __launch_bounds__(THR_MAIN, 4) sla_main(SlaP p){
  const int tid  = threadIdx.x;
  const int lane = tid & 63;
  const int wv   = tid >> 6;       // 16 waves
  const int blk  = blockIdx.x;     // 256 blocks
  __shared__ float sm[12352];      // 49.4 KB, unioned across phases
  float* smF = sm + 12288;         // P1 logits staging [30] + wsum slots

  const int ab = blk >> 2;         // attention batch
  const int aslice = blk & 3;      // attention t-slice (4 x 196)
  float svr[8];
  #pragma unroll
  for (int k = 0; k < 8; ++k) svr[k] = p.score_w[lane*8 + k];

  unsigned bid = 0;

  for (int i = 0; i <= STEPS; ++i){
    //================ Phase A: finals(i-1) + attention(i) ================
    if (i > 0 && blk < NB){
      const int fb = blk;
      for (int task = wv; task < 38; task += 16){
        const float* wrow; const float* src; float bias;
        if (task < 30){ wrow = p.sg2_w + task*512; bias = p.sg2_b[task]; src = p.h1sg + fb*512; }
        else          { wrow = p.lg2_w + (task-30)*512; bias = p.lg2_b[task-30]; src = p.h1lg + fb*512; }
        float s = 0.f;
        #pragma unroll
        for (int k = 0; k < 8; ++k) s += wrow[lane + 64*k] * cld(&src[lane + 64*k]);
        s = warp_sum(s);
        if (task < 30){ if (lane == 0) smF[task] = s + bias; }
        else if (lane == 0)
          p.out_loc[(size_t)fb*(STEPS*LREG) + (size_t)(i-1)*LREG + (task-30)] = sigmoid_fast(s + bias);
      }
    }
    __syncthreads();
    if (i > 0 && blk < NB && wv == 0){
      float sv_ = (lane < 30) ? smF[lane] : -3.4e38f;
      float m = warp_max(sv_);
      float e = (lane < 30) ? __expf(sv_ - m) : 0.f;
      float ssum = warp_sum(e);
      if (lane < 30)
        p.out_probs[(size_t)blk*(STEPS*NCLS) + (size_t)(i-1)*NCLS + lane] = e / ssum;
      int cand = (lane < 30 && sv_ == m) ? lane : 1000;
      cand = warp_min_i(cand);
      if (lane == 0) csti(&p.chars[blk], cand);
    }
    if (i == STEPS) break;
    {
      // attention: e = sum_h tanh(fp + hproj)*sv ; w = exp(e) (|e| small)
      float hpr[8];
      #pragma unroll
      for (int k = 0; k < 8; ++k) hpr[k] = cld(&p.hproj[ab*512 + lane*8 + k]);
      float acc[8] = {0,0,0,0,0,0,0,0};
      float wsr = 0.f;
      const int tl0 = aslice * 196;
      const unsigned short* fpB = (const unsigned short*)p.fp16 + ((size_t)ab*TT)*512;
      const unsigned short* ftB = (const unsigned short*)p.feat16 + ((size_t)ab*TT)*512;
      const int rc = (wv < 4) ? 13 : 12;    // 196 = 12*16 + 4
      size_t rowo = (size_t)(tl0 + wv)*512 + lane*8;
      uint4 pf = *(const uint4*)(fpB + rowo);
      uint4 pt = *(const uint4*)(ftB + rowo);
      for (int r = 0; r < rc; ++r){
        const uint4 cf = pf, ct = pt;
        if (r + 1 < rc){
          rowo += (size_t)16*512;
          pf = *(const uint4*)(fpB + rowo);
          pt = *(const uint4*)(ftB + rowo);
        }
        float e0 = 0.f, x;
        x = lo16(cf.x)+hpr[0]; e0 += tanh_fast(x)*svr[0];
        x = hi16(cf.x)+hpr[1]; e0 += tanh_fast(x)*svr[1];
        x = lo16(cf.y)+hpr[2]; e0 += tanh_fast(x)*svr[2];
        x = hi16(cf.y)+hpr[3]; e0 += tanh_fast(x)*svr[3];
        x = lo16(cf.z)+hpr[4]; e0 += tanh_fast(x)*svr[4];
        x = hi16(cf.z)+hpr[5]; e0 += tanh_fast(x)*svr[5];
        x = lo16(cf.w)+hpr[6]; e0 += tanh_fast(x)*svr[6];
        x = hi16(cf.w)+hpr[7]; e0 += tanh_fast(x)*svr[7];
        e0 = warp_sum(e0);
        float wgt = __expf(e0);
        acc[0] += wgt*lo16(ct.x); acc[1] += wgt*hi16(ct.x);
        acc[2] += wgt*lo16(ct.y); acc[3] += wgt*hi16(ct.y);
        acc[4] += wgt*lo16(ct.z); acc[5] += wgt*hi16(ct.z);
        acc[6] += wgt*lo16(ct.w); acc[7] += wgt*hi16(ct.w);
        wsr += wgt;
      }
      // two-round LDS reduction over 16 waves into smA[8][512]
      if (wv < 8){
        #pragma unroll
        for (int k = 0; k < 8; ++k) sm[wv*512 + lane*8 + k] = acc[k];
      }
      if (lane == 0) smF[32 + wv] = wsr;    // wgt is lane-uniform
      __syncthreads();
      if (wv >= 8){
        #pragma unroll
        for (int k = 0; k < 8; ++k) sm[(wv-8)*512 + lane*8 + k] += acc[k];
      }
      __syncthreads();
      if (tid < 512){
        float s = 0.f;
        #pragma unroll
        for (int r = 0; r < 8; ++r) s += sm[r*512 + tid];
        cst(&p.ctxP[((size_t)aslice*512 + tid)*64 + ab], s);
      } else if (tid == 512){
        float s = 0.f;
        #pragma unroll
        for (int r = 0; r < 16; ++r) s += smF[32 + r];
        cst(&p.wsumP[aslice*64 + ab], s);
      }
    }
    gbar(p.bar, ++bid);
    //================ Phase B: GRU, 128 blocks x 4 hidden rows ================
    if (blk < 128){
      const int j0 = blk * 4;
      const float* hidC = p.hidT + (i & 1)*(512*64);
      float accI[4][3], accH[4][3];
      #pragma unroll
      for (int jj = 0; jj < 4; ++jj)
        #pragma unroll
        for (int g = 0; g < 3; ++g){ accI[jj][g] = 0.f; accH[jj][g] = 0.f; }
      const int kb = wv * 32;
      for (int kk = 0; kk < 32; kk += 4){
        const int k = kb + kk;
        float xv[4], hv[4];
        #pragma unroll
        for (int t = 0; t < 4; ++t){
          float s = 0.f;
          #pragma unroll
          for (int sl = 0; sl < 4; ++sl) s += cld(&p.ctxP[((size_t)sl*512 + k + t)*64 + lane]);
          xv[t] = s;
          hv[t] = cld(&hidC[(k + t)*64 + lane]);
        }
        #pragma unroll
        for (int jj = 0; jj < 4; ++jj)
          #pragma unroll
          for (int g = 0; g < 3; ++g){
            const int row = g*512 + j0 + jj;
            const float4 wi = *(const float4*)&p.w_ih[(size_t)row*542 + k];
            const float4 wh = *(const float4*)&p.w_hh[(size_t)row*512 + k];
            accI[jj][g] += wi.x*xv[0] + wi.y*xv[1] + wi.z*xv[2] + wi.w*xv[3];
            accH[jj][g] += wh.x*hv[0] + wh.y*hv[1] + wh.z*hv[2] + wh.w*hv[3];
          }
      }
      // stage [8 slots][24 dots][64 lanes], two rounds
      const int slot = wv & 7;
      if (wv < 8){
        #pragma unroll
        for (int jj = 0; jj < 4; ++jj)
          #pragma unroll
          for (int g = 0; g < 3; ++g){
            sm[((slot*24) + jj*6 + g    )*64 + lane] = accI[jj][g];
            sm[((slot*24) + jj*6 + 3 + g)*64 + lane] = accH[jj][g];
          }
      }
      __syncthreads();
      if (wv >= 8){
        #pragma unroll
        for (int jj = 0; jj < 4; ++jj)
          #pragma unroll
          for (int g = 0; g < 3; ++g){
            sm[((slot*24) + jj*6 + g    )*64 + lane] += accI[jj][g];
            sm[((slot*24) + jj*6 + 3 + g)*64 + lane] += accH[jj][g];
          }
      }
      __syncthreads();
      if (tid < 256){
        const int jj = tid >> 6, b = tid & 63;
        float ws = 0.f;
        #pragma unroll
        for (int sl = 0; sl < 4; ++sl) ws += cld(&p.wsumP[sl*64 + b]);
        const float inv = 1.f / ws;
        const int ch = cldi(&p.chars[b]);
        float gi[3], gh[3];
        #pragma unroll
        for (int g = 0; g < 3; ++g){
          float giS = 0.f, ghS = 0.f;
          #pragma unroll
          for (int sl = 0; sl < 8; ++sl){
            giS += sm[((sl*24) + jj*6 + g    )*64 + b];
            ghS += sm[((sl*24) + jj*6 + 3 + g)*64 + b];
          }
          const int row = g*512 + j0 + jj;
          gi[g] = giS*inv + p.w_ih[(size_t)row*542 + 512 + ch] + p.b_ih[row];
          gh[g] = ghS + p.b_hh[row];
        }
        float r_ = sigmoid_fast(gi[0] + gh[0]);
        float z_ = sigmoid_fast(gi[1] + gh[1]);
        float n_ = tanh_fast(gi[2] + r_*gh[2]);
        float hold = cld(&hidC[(j0 + jj)*64 + b]);
        cst(&p.hidT[((i+1) & 1)*(512*64) + (j0 + jj)*64 + b], (1.f - z_)*n_ + z_*hold);
      }
    } else {
      __syncthreads();
    }
    gbar(p.bar, ++bid);
    //================ Phase C: heads, 128 blocks x 12 rows ================
    if (blk < 128){
      const int r0 = blk * 12;            // global rows [r0, r0+12)
      const float* hidN = p.hidT + ((i+1) & 1)*(512*64);
      const float* rowp[12];
      #pragma unroll
      for (int r = 0; r < 12; ++r){
        const int rg = r0 + r, head = rg >> 9, j = rg & 511;
        const float* base = (head == 0) ? p.h2h_w : (head == 1) ? p.sg1_w : p.lg1_w;
        rowp[r] = base + (size_t)j*512;
      }
      float acc[12];
      #pragma unroll
      for (int r = 0; r < 12; ++r) acc[r] = 0.f;
      const int kb = wv * 32;
      for (int kk = 0; kk < 32; kk += 4){
        const int k = kb + kk;
        float hv[4];
        #pragma unroll
        for (int t = 0; t < 4; ++t) hv[t] = cld(&hidN[(k + t)*64 + lane]);
        #pragma unroll
        for (int r = 0; r < 12; ++r){
          const float4 w4 = *(const float4*)&rowp[r][k];
          acc[r] += w4.x*hv[0] + w4.y*hv[1] + w4.z*hv[2] + w4.w*hv[3];
        }
      }
      const int slot = wv & 7;
      if (wv < 8){
        #pragma unroll
        for (int r = 0; r < 12; ++r) sm[((slot*12) + r)*64 + lane] = acc[r];
      }
      __syncthreads();
      if (wv >= 8){
        #pragma unroll
        for (int r = 0; r < 12; ++r) sm[((slot*12) + r)*64 + lane] += acc[r];
      }
      __syncthreads();
      if (tid < 768){
        const int r = tid >> 6, b = tid & 63;
        float s = 0.f;
        #pragma unroll
        for (int sl = 0; sl < 8; ++sl) s += sm[((sl*12) + r)*64 + b];
        const int rg = r0 + r, head = rg >> 9, j = rg & 511;
        const float bias = (head == 0) ? p.h2h_b[j] : (head == 1) ? p.sg1_b[j] : p.lg1_b[j];
        float* dst = (head == 0) ? p.hproj : (head == 1) ? p.h1sg : p.h1lg;
        cst(&dst[b*512 + j], s + bias);
      }
    } else {
      __syncthreads(); __syncthreads();
    }
    gbar(p.bar, ++bid);
  }
}

extern "C" void kernel_launch(void* const* d_in, const int* in_sizes, int n_in,
                              void* d_out, int out_size, void* d_ws, size_t ws_size,
                              hipStream_t stream){
  (void)in_sizes; (void)n_in; (void)out_size; (void)ws_size;
  char* w = (char*)d_ws;
  size_t off = 0;
  auto carve = [&](size_t bytes) -> char* {
    char* r = w + off; off += (bytes + 255) & ~(size_t)255; return r;
  };
  SlaP p;
  p.feat16 = (__hip_bfloat16*)carve((size_t)NB*TT*CC*2);
  p.fp16   = (__hip_bfloat16*)carve((size_t)NB*TT*HH*2);
  p.hidT   = (float*)carve((size_t)2*512*64*4);
  p.hproj  = (float*)carve((size_t)64*512*4);
  p.h1sg   = (float*)carve((size_t)64*512*4);
  p.h1lg   = (float*)carve((size_t)64*512*4);
  p.ctxP   = (float*)carve((size_t)4*512*64*4);
  p.wsumP  = (float*)carve(4*64*4);
  p.chars  = (int*)carve(64*4);
  p.bar    = (unsigned*)carve(2048);

  p.score_w = (const float*)d_in[4];
  p.w_ih  = (const float*)d_in[5];  p.w_hh  = (const float*)d_in[6];
  p.b_ih  = (const float*)d_in[7];  p.b_hh  = (const float*)d_in[8];
  p.h2h_w = (const float*)d_in[2];  p.h2h_b = (const float*)d_in[3];
  p.sg1_w = (const float*)d_in[9];  p.sg1_b = (const float*)d_in[10];
  p.sg2_w = (const float*)d_in[11]; p.sg2_b = (const float*)d_in[12];
  p.lg1_w = (const float*)d_in[13]; p.lg1_b = (const float*)d_in[14];
  p.lg2_w = (const float*)d_in[15]; p.lg2_b = (const float*)d_in[16];
  p.out_probs = (float*)d_out;
  p.out_loc   = p.out_probs + (size_t)NB*STEPS*NCLS;

  const float* fea = (const float*)d_in[0];
  const float* i2h = (const float*)d_in[1];

  k_init<<<128, 256, 0, stream>>>(p);
  k_transpose<<<dim3(13, 8, 64), 256, 0, stream>>>(fea, p.feat16);
  k_fpgemm<<<dim3(13, 8, 64), 256, 0, stream>>>(fea, i2h, p.fp16);
  sla_main<<<GRID_MAIN, THR_MAIN, 0, stream>>>(p);
}

// Round 3
// 38801.758 us; speedup vs baseline: 2.3267x; 1.2182x over previous
//
#include <hip/hip_runtime.h>
#include <hip/hip_bf16.h>

// SLAHead decode: B=64, T=784, C=H=512, 501 steps.
// Persistent kernel, 256 blocks x 1024 thr (1 block/CU co-resident).
// Relaxed agent-scope atomics only (no fences / no L2 wb-inv scans).
// R3: depth-2x2-row attention prefetch; ctx combined via unsafeAtomicAdd;
// all cross-block activations in [k/2][b][2] layout with 8B coherent ld/st.

#define NB 64
#define TT 784
#define CC 512
#define HH 512
#define NCLS 30
#define LREG 8
#define STEPS 501
#define GRID_MAIN 256
#define THR_MAIN 1024

struct SlaP {
  __hip_bfloat16* feat16;   // [B][T][C]
  __hip_bfloat16* fp16;     // [B][T][H]
  float* hid2;              // [2][H/2][B][2] ping-pong, pair-interleaved
  float* hproj;             // [B][H]
  float* h1sg;              // [B][H]
  float* h1lg;              // [B][H]
  float* ctx2;              // [C/2][B][2] combined raw context (atomicAdd)
  float* wsum;              // [B]
  int*   chars;             // [B]
  unsigned* bar;            // [0]=master cnt, [64]=gen, [8+32x]=per-XCD cnt
  const float *score_w, *w_ih, *w_hh, *b_ih, *b_hh;
  const float *h2h_w, *h2h_b, *sg1_w, *sg1_b, *sg2_w, *sg2_b;
  const float *lg1_w, *lg1_b, *lg2_w, *lg2_b;
  float *out_probs, *out_loc;
};

__device__ __forceinline__ float lo16(unsigned v){ return __uint_as_float(v << 16); }
__device__ __forceinline__ float hi16(unsigned v){ return __uint_as_float(v & 0xffff0000u); }

__device__ __forceinline__ float cld(const float* p){
  return __hip_atomic_load(p, __ATOMIC_RELAXED, __HIP_MEMORY_SCOPE_AGENT);
}
__device__ __forceinline__ void cst(float* p, float v){
  __hip_atomic_store(p, v, __ATOMIC_RELAXED, __HIP_MEMORY_SCOPE_AGENT);
}
__device__ __forceinline__ int cldi(const int* p){
  return __hip_atomic_load(p, __ATOMIC_RELAXED, __HIP_MEMORY_SCOPE_AGENT);
}
__device__ __forceinline__ void csti(int* p, int v){
  __hip_atomic_store(p, v, __ATOMIC_RELAXED, __HIP_MEMORY_SCOPE_AGENT);
}
__device__ __forceinline__ float2 cld2(const float* p){
  unsigned long long v = __hip_atomic_load((const unsigned long long*)p,
                          __ATOMIC_RELAXED, __HIP_MEMORY_SCOPE_AGENT);
  union { unsigned long long u; float2 f; } c; c.u = v; return c.f;
}
__device__ __forceinline__ void cst2(float* p, float a, float b){
  union { unsigned long long u; float2 f; } c; c.f = make_float2(a, b);
  __hip_atomic_store((unsigned long long*)p, c.u,
                     __ATOMIC_RELAXED, __HIP_MEMORY_SCOPE_AGENT);
}

__device__ __forceinline__ float tanh_fast(float x){
  float ex = __expf(2.f * x);
  return 1.f - 2.f * __builtin_amdgcn_rcpf(ex + 1.f);
}
__device__ __forceinline__ float sigmoid_fast(float x){
  return __builtin_amdgcn_rcpf(1.f + __expf(-x));
}
__device__ __forceinline__ float warp_sum(float v){
  #pragma unroll
  for (int m = 32; m > 0; m >>= 1) v += __shfl_xor(v, m, 64);
  return v;
}
__device__ __forceinline__ void warp_sum2(float& a, float& b){
  #pragma unroll
  for (int m = 32; m > 0; m >>= 1){
    float ta = __shfl_xor(a, m, 64);
    float tb = __shfl_xor(b, m, 64);
    a += ta; b += tb;
  }
}
__device__ __forceinline__ float warp_max(float v){
  #pragma unroll
  for (int m = 32; m > 0; m >>= 1) v = fmaxf(v, __shfl_xor(v, m, 64));
  return v;
}
__device__ __forceinline__ int warp_min_i(int v){
  #pragma unroll
  for (int m = 32; m > 0; m >>= 1) v = min(v, __shfl_xor(v, m, 64));
  return v;
}

// Monotone fence-free grid barrier (relaxed agent atomics only).
__device__ __forceinline__ void gbar(unsigned* bar, unsigned target){
  __syncthreads();
  if (threadIdx.x == 0){
    unsigned* c8 = bar + 8 + (blockIdx.x & 7) * 32;
    unsigned p = __hip_atomic_fetch_add(c8, 1u, __ATOMIC_RELAXED, __HIP_MEMORY_SCOPE_AGENT);
    if (p == 32u * target - 1u){
      unsigned pm = __hip_atomic_fetch_add(bar, 1u, __ATOMIC_RELAXED, __HIP_MEMORY_SCOPE_AGENT);
      if (pm == 8u * target - 1u)
        __hip_atomic_store(bar + 64, target, __ATOMIC_RELAXED, __HIP_MEMORY_SCOPE_AGENT);
    }
    while (__hip_atomic_load(bar + 64, __ATOMIC_RELAXED, __HIP_MEMORY_SCOPE_AGENT) < target)
      __builtin_amdgcn_s_sleep(1);
  }
  __syncthreads();
}

// ---------------- setup kernels ----------------

__global__ void k_init(SlaP p){
  int idx = blockIdx.x * blockDim.x + threadIdx.x;  // 32768 threads
  if (idx < 32768){ p.hid2[idx] = 0.f; p.ctx2[idx] = 0.f; }
  if (idx < 64*512) p.hproj[idx] = p.h2h_b[idx & 511];
  if (idx < 64){ p.wsum[idx] = 0.f; p.chars[idx] = 0; }
  if (idx < 512) p.bar[idx] = 0u;
}

__global__ void k_transpose(const float* __restrict__ fea, __hip_bfloat16* __restrict__ feat16){
  __shared__ float tile[64][65];
  const int b = blockIdx.z, t0 = blockIdx.x * 64, c0 = blockIdx.y * 64;
  #pragma unroll
  for (int r = 0; r < 16; ++r){
    int idx = threadIdx.x + 256*r;
    int ci = idx >> 6, tj = idx & 63;
    float v = 0.f;
    if (t0 + tj < TT) v = fea[((size_t)b*CC + (c0+ci))*TT + t0 + tj];
    tile[ci][tj] = v;
  }
  __syncthreads();
  #pragma unroll
  for (int r = 0; r < 16; ++r){
    int idx = threadIdx.x + 256*r;
    int tj = idx >> 6, ci = idx & 63;
    if (t0 + tj < TT)
      feat16[((size_t)b*TT + t0 + tj)*CC + c0 + ci] = __float2bfloat16(tile[ci][tj]);
  }
}

__global__ void k_fpgemm(const float* __restrict__ fea, const float* __restrict__ i2h,
                         __hip_bfloat16* __restrict__ fp16){
  const int b = blockIdx.z, t0 = blockIdx.x * 64, h0 = blockIdx.y * 64;
  const int tx = threadIdx.x & 15, ty = threadIdx.x >> 4;
  const int tb = t0 + tx*4, hb = h0 + ty*4;
  const int ts = (tb < TT) ? tb : 0;
  const float* A = fea + (size_t)b*CC*TT;
  float acc[4][4];
  #pragma unroll
  for (int j = 0; j < 4; ++j)
    #pragma unroll
    for (int i2 = 0; i2 < 4; ++i2) acc[j][i2] = 0.f;
  for (int k = 0; k < CC; ++k){
    const float4 a4 = *(const float4*)&A[(size_t)k*TT + ts];
    float bv0 = i2h[(size_t)(hb+0)*CC + k];
    float bv1 = i2h[(size_t)(hb+1)*CC + k];
    float bv2 = i2h[(size_t)(hb+2)*CC + k];
    float bv3 = i2h[(size_t)(hb+3)*CC + k];
    acc[0][0] += bv0*a4.x; acc[0][1] += bv0*a4.y; acc[0][2] += bv0*a4.z; acc[0][3] += bv0*a4.w;
    acc[1][0] += bv1*a4.x; acc[1][1] += bv1*a4.y; acc[1][2] += bv1*a4.z; acc[1][3] += bv1*a4.w;
    acc[2][0] += bv2*a4.x; acc[2][1] += bv2*a4.y; acc[2][2] += bv2*a4.z; acc[2][3] += bv2*a4.w;
    acc[3][0] += bv3*a4.x; acc[3][1] += bv3*a4.y; acc[3][2] += bv3*a4.z; acc[3][3] += bv3*a4.w;
  }
  if (tb < TT){
    #pragma unroll
    for (int j = 0; j < 4; ++j)
      #pragma unroll
      for (int i2 = 0; i2 < 4; ++i2)
        fp16[((size_t)b*TT + tb + i2)*CC + hb + j] = __float2bfloat16(acc[j][i2]);
  }
}

// ---------------- persistent decode kernel ----------------

__global__ void __launch_bounds__(THR_MAIN, 4) sla_main(SlaP p){
  const int tid  = threadIdx.x;
  const int lane = tid & 63;
  const int wv   = tid >> 6;       // 16 waves
  const int blk  = blockIdx.x;     // 256 blocks
  __shared__ float sm[12352];      // 49.4 KB
  float* smF = sm + 12288;

  const int ab = blk >> 2;         // attention batch
  const int aslice = blk & 3;      // attention t-slice (4 x 196)
  float svr[8];
  #pragma unroll
  for (int k = 0; k < 8; ++k) svr[k] = p.score_w[lane*8 + k];

  unsigned bid = 0;

  for (int i = 0; i <= STEPS; ++i){
    //================ Phase A: finals(i-1) + attention(i) ================
    if (i > 0 && blk < NB){
      const int fb = blk;
      for (int task = wv; task < 38; task += 16){
        const float* wrow; const float* src; float bias;
        if (task < 30){ wrow = p.sg2_w + task*512; bias = p.sg2_b[task]; src = p.h1sg + fb*512; }
        else          { wrow = p.lg2_w + (task-30)*512; bias = p.lg2_b[task-30]; src = p.h1lg + fb*512; }
        float s = 0.f;
        #pragma unroll
        for (int kq = 0; kq < 4; ++kq){
          const float2 wv2 = *(const float2*)&wrow[lane*2 + 128*kq];
          const float2 sv2 = cld2(&src[lane*2 + 128*kq]);
          s += wv2.x*sv2.x + wv2.y*sv2.y;
        }
        s = warp_sum(s);
        if (task < 30){ if (lane == 0) smF[task] = s + bias; }
        else if (lane == 0)
          p.out_loc[(size_t)fb*(STEPS*LREG) + (size_t)(i-1)*LREG + (task-30)] = sigmoid_fast(s + bias);
      }
    }
    __syncthreads();
    if (i > 0 && blk < NB && wv == 0){
      float sv_ = (lane < 30) ? smF[lane] : -3.4e38f;
      float m = warp_max(sv_);
      float e = (lane < 30) ? __expf(sv_ - m) : 0.f;
      float ssum = warp_sum(e);
      if (lane < 30)
        p.out_probs[(size_t)blk*(STEPS*NCLS) + (size_t)(i-1)*NCLS + lane] = e / ssum;
      int cand = (lane < 30 && sv_ == m) ? lane : 1000;
      cand = warp_min_i(cand);
      if (lane == 0) csti(&p.chars[blk], cand);
    }
    if (i == STEPS) break;
    {
      // attention: e = sum_h tanh(fp + hproj)*sv ; w = exp(e)
      float hpr[8];
      #pragma unroll
      for (int k = 0; k < 4; ++k){
        float2 h2 = cld2(&p.hproj[ab*512 + lane*8 + 2*k]);
        hpr[2*k] = h2.x; hpr[2*k+1] = h2.y;
      }
      float acc[8] = {0,0,0,0,0,0,0,0};
      float wsr = 0.f;
      const int tl0 = aslice * 196;
      const unsigned short* fpB = (const unsigned short*)p.fp16 + ((size_t)ab*TT)*512;
      const unsigned short* ftB = (const unsigned short*)p.feat16 + ((size_t)ab*TT)*512;
      const int cnt = (wv < 4) ? 13 : 12;           // 196 = 4*13 + 12*12
      const int r0r = wv*12 + ((wv < 4) ? wv : 4);
      const unsigned short* fpR = fpB + (size_t)(tl0 + r0r)*512 + lane*8;
      const unsigned short* ftR = ftB + (size_t)(tl0 + r0r)*512 + lane*8;
      uint4 f0 = *(const uint4*)(fpR);
      uint4 g0 = *(const uint4*)(ftR);
      uint4 f1 = *(const uint4*)(fpR + 512);
      uint4 g1 = *(const uint4*)(ftR + 512);
      const int np = cnt >> 1;                       // 6
      for (int pi = 0; pi < np; ++pi){
        const uint4 cf0 = f0, cg0 = g0, cf1 = f1, cg1 = g1;
        fpR += 1024; ftR += 1024;
        if (pi + 1 < np){
          f0 = *(const uint4*)(fpR);       g0 = *(const uint4*)(ftR);
          f1 = *(const uint4*)(fpR + 512); g1 = *(const uint4*)(ftR + 512);
        } else if (cnt & 1){
          f0 = *(const uint4*)(fpR);       g0 = *(const uint4*)(ftR);
        }
        float ea = 0.f, eb = 0.f, x;
        x = lo16(cf0.x)+hpr[0]; ea += tanh_fast(x)*svr[0];
        x = lo16(cf1.x)+hpr[0]; eb += tanh_fast(x)*svr[0];
        x = hi16(cf0.x)+hpr[1]; ea += tanh_fast(x)*svr[1];
        x = hi16(cf1.x)+hpr[1]; eb += tanh_fast(x)*svr[1];
        x = lo16(cf0.y)+hpr[2]; ea += tanh_fast(x)*svr[2];
        x = lo16(cf1.y)+hpr[2]; eb += tanh_fast(x)*svr[2];
        x = hi16(cf0.y)+hpr[3]; ea += tanh_fast(x)*svr[3];
        x = hi16(cf1.y)+hpr[3]; eb += tanh_fast(x)*svr[3];
        x = lo16(cf0.z)+hpr[4]; ea += tanh_fast(x)*svr[4];
        x = lo16(cf1.z)+hpr[4]; eb += tanh_fast(x)*svr[4];
        x = hi16(cf0.z)+hpr[5]; ea += tanh_fast(x)*svr[5];
        x = hi16(cf1.z)+hpr[5]; eb += tanh_fast(x)*svr[5];
        x = lo16(cf0.w)+hpr[6]; ea += tanh_fast(x)*svr[6];
        x = lo16(cf1.w)+hpr[6]; eb += tanh_fast(x)*svr[6];
        x = hi16(cf0.w)+hpr[7]; ea += tanh_fast(x)*svr[7];
        x = hi16(cf1.w)+hpr[7]; eb += tanh_fast(x)*svr[7];
        warp_sum2(ea, eb);
        const float wa = __expf(ea), wb = __expf(eb);
        acc[0] += wa*lo16(cg0.x) + wb*lo16(cg1.x);
        acc[1] += wa*hi16(cg0.x) + wb*hi16(cg1.x);
        acc[2] += wa*lo16(cg0.y) + wb*lo16(cg1.y);
        acc[3] += wa*hi16(cg0.y) + wb*hi16(cg1.y);
        acc[4] += wa*lo16(cg0.z) + wb*lo16(cg1.z);
        acc[5] += wa*hi16(cg0.z) + wb*hi16(cg1.z);
        acc[6] += wa*lo16(cg0.w) + wb*lo16(cg1.w);
        acc[7] += wa*hi16(cg0.w) + wb*hi16(cg1.w);
        wsr += wa + wb;
      }
      if (cnt & 1){
        float e0 = 0.f, x;
        x = lo16(f0.x)+hpr[0]; e0 += tanh_fast(x)*svr[0];
        x = hi16(f0.x)+hpr[1]; e0 += tanh_fast(x)*svr[1];
        x = lo16(f0.y)+hpr[2]; e0 += tanh_fast(x)*svr[2];
        x = hi16(f0.y)+hpr[3]; e0 += tanh_fast(x)*svr[3];
        x = lo16(f0.z)+hpr[4]; e0 += tanh_fast(x)*svr[4];
        x = hi16(f0.z)+hpr[5]; e0 += tanh_fast(x)*svr[5];
        x = lo16(f0.w)+hpr[6]; e0 += tanh_fast(x)*svr[6];
        x = hi16(f0.w)+hpr[7]; e0 += tanh_fast(x)*svr[7];
        e0 = warp_sum(e0);
        const float wa = __expf(e0);
        acc[0] += wa*lo16(g0.x); acc[1] += wa*hi16(g0.x);
        acc[2] += wa*lo16(g0.y); acc[3] += wa*hi16(g0.y);
        acc[4] += wa*lo16(g0.z); acc[5] += wa*hi16(g0.z);
        acc[6] += wa*lo16(g0.w); acc[7] += wa*hi16(g0.w);
        wsr += wa;
      }
      // two-round LDS reduction over 16 waves into sm[8][512]
      if (wv < 8){
        #pragma unroll
        for (int k = 0; k < 8; ++k) sm[wv*512 + lane*8 + k] = acc[k];
      }
      if (lane == 0) smF[32 + wv] = wsr;
      __syncthreads();
      if (wv >= 8){
        #pragma unroll
        for (int k = 0; k < 8; ++k) sm[(wv-8)*512 + lane*8 + k] += acc[k];
      }
      __syncthreads();
      if (tid < 512){
        float s = 0.f;
        #pragma unroll
        for (int r = 0; r < 8; ++r) s += sm[r*512 + tid];
        unsafeAtomicAdd(&p.ctx2[(tid >> 1)*128 + ab*2 + (tid & 1)], s);
      } else if (tid == 512){
        float s = 0.f;
        #pragma unroll
        for (int r = 0; r < 16; ++r) s += smF[32 + r];
        unsafeAtomicAdd(&p.wsum[ab], s);
      }
    }
    gbar(p.bar, ++bid);
    //================ Phase B: GRU, 128 blocks x 4 hidden rows ================
    if (blk < 128){
      const int j0 = blk * 4;
      const float* hidC = p.hid2 + (i & 1)*(512*64);
      float accI[4][3], accH[4][3];
      #pragma unroll
      for (int jj = 0; jj < 4; ++jj)
        #pragma unroll
        for (int g = 0; g < 3; ++g){ accI[jj][g] = 0.f; accH[jj][g] = 0.f; }
      const int kb = wv * 32;
      for (int kk = 0; kk < 32; kk += 4){
        const int k = kb + kk;
        const float2 x01 = cld2(&p.ctx2[(k >> 1)*128 + lane*2]);
        const float2 x23 = cld2(&p.ctx2[(k >> 1)*128 + 128 + lane*2]);
        const float2 h01 = cld2(&hidC[(k >> 1)*128 + lane*2]);
        const float2 h23 = cld2(&hidC[(k >> 1)*128 + 128 + lane*2]);
        #pragma unroll
        for (int jj = 0; jj < 4; ++jj)
          #pragma unroll
          for (int g = 0; g < 3; ++g){
            const int row = g*512 + j0 + jj;
            const float4 wi = *(const float4*)&p.w_ih[(size_t)row*542 + k];
            const float4 wh = *(const float4*)&p.w_hh[(size_t)row*512 + k];
            accI[jj][g] += wi.x*x01.x + wi.y*x01.y + wi.z*x23.x + wi.w*x23.y;
            accH[jj][g] += wh.x*h01.x + wh.y*h01.y + wh.z*h23.x + wh.w*h23.y;
          }
      }
      const int slot = wv & 7;
      if (wv < 8){
        #pragma unroll
        for (int jj = 0; jj < 4; ++jj)
          #pragma unroll
          for (int g = 0; g < 3; ++g){
            sm[((slot*24) + jj*6 + g    )*64 + lane] = accI[jj][g];
            sm[((slot*24) + jj*6 + 3 + g)*64 + lane] = accH[jj][g];
          }
      }
      __syncthreads();
      if (wv >= 8){
        #pragma unroll
        for (int jj = 0; jj < 4; ++jj)
          #pragma unroll
          for (int g = 0; g < 3; ++g){
            sm[((slot*24) + jj*6 + g    )*64 + lane] += accI[jj][g];
            sm[((slot*24) + jj*6 + 3 + g)*64 + lane] += accH[jj][g];
          }
      }
      __syncthreads();
      if (tid < 128){
        const int pp = tid >> 6;            // j-pair 0..1 (rows j0+2pp, j0+2pp+1)
        const int b = tid & 63;
        float ws = 0.f;
        ws = cld(&p.wsum[b]);
        const float inv = 1.f / ws;
        const int ch = cldi(&p.chars[b]);
        const float2 ho = cld2(&hidC[((j0 >> 1) + pp)*128 + b*2]);
        float nh[2];
        #pragma unroll
        for (int q = 0; q < 2; ++q){
          const int jj = pp*2 + q;
          float gi[3], gh[3];
          #pragma unroll
          for (int g = 0; g < 3; ++g){
            float giS = 0.f, ghS = 0.f;
            #pragma unroll
            for (int sl = 0; sl < 8; ++sl){
              giS += sm[((sl*24) + jj*6 + g    )*64 + b];
              ghS += sm[((sl*24) + jj*6 + 3 + g)*64 + b];
            }
            const int row = g*512 + j0 + jj;
            gi[g] = giS*inv + p.w_ih[(size_t)row*542 + 512 + ch] + p.b_ih[row];
            gh[g] = ghS + p.b_hh[row];
          }
          float r_ = sigmoid_fast(gi[0] + gh[0]);
          float z_ = sigmoid_fast(gi[1] + gh[1]);
          float n_ = tanh_fast(gi[2] + r_*gh[2]);
          float hold = (q == 0) ? ho.x : ho.y;
          nh[q] = (1.f - z_)*n_ + z_*hold;
        }
        cst2(&p.hid2[((i+1) & 1)*(512*64) + ((j0 >> 1) + pp)*128 + b*2], nh[0], nh[1]);
      }
    } else {
      __syncthreads(); __syncthreads();
    }
    gbar(p.bar, ++bid);
    //================ Phase C: heads, 128 blocks x 12 rows; idle blocks zero ctx ================
    if (blk < 128){
      const int r0 = blk * 12;
      const float* hidN = p.hid2 + ((i+1) & 1)*(512*64);
      const float* rowp[12];
      #pragma unroll
      for (int r = 0; r < 12; ++r){
        const int rg = r0 + r, head = rg >> 9, j = rg & 511;
        const float* base = (head == 0) ? p.h2h_w : (head == 1) ? p.sg1_w : p.lg1_w;
        rowp[r] = base + (size_t)j*512;
      }
      float acc[12];
      #pragma unroll
      for (int r = 0; r < 12; ++r) acc[r] = 0.f;
      const int kb = wv * 32;
      for (int kk = 0; kk < 32; kk += 4){
        const int k = kb + kk;
        const float2 h01 = cld2(&hidN[(k >> 1)*128 + lane*2]);
        const float2 h23 = cld2(&hidN[(k >> 1)*128 + 128 + lane*2]);
        #pragma unroll
        for (int r = 0; r < 12; ++r){
          const float4 w4 = *(const float4*)&rowp[r][k];
          acc[r] += w4.x*h01.x + w4.y*h01.y + w4.z*h23.x + w4.w*h23.y;
        }
      }
      const int slot = wv & 7;
      if (wv < 8){
        #pragma unroll
        for (int r = 0; r < 12; ++r) sm[((slot*12) + r)*64 + lane] = acc[r];
      }
      __syncthreads();
      if (wv >= 8){
        #pragma unroll
        for (int r = 0; r < 12; ++r) sm[((slot*12) + r)*64 + lane] += acc[r];
      }
      __syncthreads();
      if (tid < 384){
        const int q = tid >> 6, b = tid & 63;   // row pair (2q, 2q+1)
        float s0 = 0.f, s1 = 0.f;
        #pragma unroll
        for (int sl = 0; sl < 8; ++sl){
          s0 += sm[((sl*12) + 2*q    )*64 + b];
          s1 += sm[((sl*12) + 2*q + 1)*64 + b];
        }
        const int rg = r0 + 2*q, head = rg >> 9, j = rg & 511;
        const float* bb = (head == 0) ? p.h2h_b : (head == 1) ? p.sg1_b : p.lg1_b;
        float* dst = (head == 0) ? p.hproj : (head == 1) ? p.h1sg : p.h1lg;
        cst2(&dst[b*512 + j], s0 + bb[j], s1 + bb[j+1]);
      }
    } else {
      const int bz = blk - 128;
      if (tid < 256) cst(&p.ctx2[bz*256 + tid], 0.f);
      if (bz == 127 && tid < 64) cst(&p.wsum[tid], 0.f);
      __syncthreads(); __syncthreads();
    }
    gbar(p.bar, ++bid);
  }
}

extern "C" void kernel_launch(void* const* d_in, const int* in_sizes, int n_in,
                              void* d_out, int out_size, void* d_ws, size_t ws_size,
                              hipStream_t stream){
  (void)in_sizes; (void)n_in; (void)out_size; (void)ws_size;
  char* w = (char*)d_ws;
  size_t off = 0;
  auto carve = [&](size_t bytes) -> char* {
    char* r = w + off; off += (bytes + 255) & ~(size_t)255; return r;
  };
  SlaP p;
  p.feat16 = (__hip_bfloat16*)carve((size_t)NB*TT*CC*2);
  p.fp16   = (__hip_bfloat16*)carve((size_t)NB*TT*HH*2);
  p.hid2   = (float*)carve((size_t)2*512*64*4);
  p.hproj  = (float*)carve((size_t)64*512*4);
  p.h1sg   = (float*)carve((size_t)64*512*4);
  p.h1lg   = (float*)carve((size_t)64*512*4);
  p.ctx2   = (float*)carve((size_t)512*64*4);
  p.wsum   = (float*)carve(64*4);
  p.chars  = (int*)carve(64*4);
  p.bar    = (unsigned*)carve(2048);

  p.score_w = (const float*)d_in[4];
  p.w_ih  = (const float*)d_in[5];  p.w_hh  = (const float*)d_in[6];
  p.b_ih  = (const float*)d_in[7];  p.b_hh  = (const float*)d_in[8];
  p.h2h_w = (const float*)d_in[2];  p.h2h_b = (const float*)d_in[3];
  p.sg1_w = (const float*)d_in[9];  p.sg1_b = (const float*)d_in[10];
  p.sg2_w = (const float*)d_in[11]; p.sg2_b = (const float*)d_in[12];
  p.lg1_w = (const float*)d_in[13]; p.lg1_b = (const float*)d_in[14];
  p.lg2_w = (const float*)d_in[15]; p.lg2_b = (const float*)d_in[16];
  p.out_probs = (float*)d_out;
  p.out_loc   = p.out_probs + (size_t)NB*STEPS*NCLS;

  const float* fea = (const float*)d_in[0];
  const float* i2h = (const float*)d_in[1];

  k_init<<<128, 256, 0, stream>>>(p);
  k_transpose<<<dim3(13, 8, 64), 256, 0, stream>>>(fea, p.feat16);
  k_fpgemm<<<dim3(13, 8, 64), 256, 0, stream>>>(fea, i2h, p.fp16);
  sla_main<<<GRID_MAIN, THR_MAIN, 0, stream>>>(p);
}